// Round 1
// baseline (179.347 us; speedup 1.0000x reference)
//
#include <hip/hip_runtime.h>
#include <hip/hip_bf16.h>

#define N_HALF 4096
#define M_TOT  8192
#define D      256
#define TI     64
#define TJ     64
#define JCHUNK 1024
#define ZJ_STRIDE 264   // 256 + 8 bf16 pad: keeps 16B alignment, breaks bank conflicts

typedef __attribute__((ext_vector_type(8))) short bf16x8;
typedef __attribute__((ext_vector_type(4))) float f32x4;

__device__ __forceinline__ float wave_reduce_sum(float v) {
    v += __shfl_xor(v, 1);
    v += __shfl_xor(v, 2);
    v += __shfl_xor(v, 4);
    v += __shfl_xor(v, 8);
    v += __shfl_xor(v, 16);
    v += __shfl_xor(v, 32);
    return v;
}

__global__ void k_init(float* __restrict__ p, int n) {
    int i = blockIdx.x * 256 + threadIdx.x;
    if (i < n) p[i] = 0.0f;
}

// One block per row of reps = concat([zjs, zis]). Normalize with eps-clamped
// norm (matches nn.CosineSimilarity), store bf16.
__global__ void k_norm(const float* __restrict__ zis, const float* __restrict__ zjs,
                       __hip_bfloat16* __restrict__ zn) {
    int r = blockIdx.x;
    int t = threadIdx.x;
    const float* src = (r < N_HALF) ? (zjs + (size_t)r * D)
                                    : (zis + (size_t)(r - N_HALF) * D);
    float x = src[t];
    float ss = wave_reduce_sum(x * x);
    __shared__ float wsum[4];
    if ((t & 63) == 0) wsum[t >> 6] = ss;
    __syncthreads();
    float tot = wsum[0] + wsum[1] + wsum[2] + wsum[3];
    float nrm = fmaxf(sqrtf(tot), 1e-8f);
    zn[(size_t)r * D + t] = __float2bfloat16(x / nrm);
}

// One wave per positive pair (i, i+N). Sum over all rows of pos_i = sim/T,
// each unordered pair counted twice -> contribution = dot * (2/T) = dot * 4.
__global__ void k_pos(const __hip_bfloat16* __restrict__ zn, float* __restrict__ pos_sum) {
    int gw   = (blockIdx.x * 256 + threadIdx.x) >> 6;  // 0..4095
    int lane = threadIdx.x & 63;
    const __hip_bfloat16* a = zn + (size_t)gw * D + lane * 4;
    const __hip_bfloat16* b = zn + (size_t)(gw + N_HALF) * D + lane * 4;
    float d = 0.0f;
#pragma unroll
    for (int k = 0; k < 4; ++k)
        d += __bfloat162float(a[k]) * __bfloat162float(b[k]);
    d = wave_reduce_sum(d);
    if (lane == 0) atomicAdd(pos_sum, d * 4.0f);
}

// Fused sim + exp + row-sum. Block tile: 64 i-rows x 1024 j-cols.
// Wave w owns i-rows [w*16, w*16+16); A-frags for full K=256 live in registers.
// B tiles (64 j-rows x 256) staged in LDS per sub-tile.
// rowsum[i] += sum_j exp(sim_ij*2 - 2)   (includes diag; subtract 1 later)
__global__ __launch_bounds__(256, 4)
void k_main(const __hip_bfloat16* __restrict__ znh, float* __restrict__ rowsum) {
    __shared__ __align__(16) ushort zj[TJ * ZJ_STRIDE];
    const ushort* zn = reinterpret_cast<const ushort*>(znh);
    int i0   = blockIdx.x * TI;
    int j0   = blockIdx.y * JCHUNK;
    int tid  = threadIdx.x;
    int wave = tid >> 6;
    int lane = tid & 63;
    int q    = lane >> 4;   // quad
    int li   = lane & 15;

    // A fragment layout (16x16x32 bf16): A[m][k], m = lane&15, k = quad*8 + j
    bf16x8 afrag[8];
    {
        const ushort* ap = zn + (((size_t)(i0 + wave * 16 + li)) << 8) + q * 8;
#pragma unroll
        for (int kt = 0; kt < 8; ++kt)
            afrag[kt] = *reinterpret_cast<const bf16x8*>(ap + kt * 32);
    }

    float part[4] = {0.0f, 0.0f, 0.0f, 0.0f};

    for (int jt = 0; jt < JCHUNK / TJ; ++jt) {
        __syncthreads();   // previous iteration's compute done before overwrite
        {
            int base = j0 + jt * TJ;
#pragma unroll
            for (int it = 0; it < 8; ++it) {
                int e  = (it * 256 + tid) * 8;   // 64*256 elems / (256 thr * 8/thr) = 8 iters
                int rr = e >> 8;
                int cc = e & 255;
                *reinterpret_cast<uint4*>(&zj[rr * ZJ_STRIDE + cc]) =
                    *reinterpret_cast<const uint4*>(zn + (((size_t)(base + rr)) << 8) + cc);
            }
        }
        __syncthreads();

        f32x4 acc0 = {0.0f, 0.0f, 0.0f, 0.0f};
        f32x4 acc1 = {0.0f, 0.0f, 0.0f, 0.0f};
        f32x4 acc2 = {0.0f, 0.0f, 0.0f, 0.0f};
        f32x4 acc3 = {0.0f, 0.0f, 0.0f, 0.0f};
#pragma unroll
        for (int kt = 0; kt < 8; ++kt) {
            // B fragment: B[k][n], n = lane&15 -> zj row (jtt*16 + li), k = kt*32 + q*8
            const ushort* bp = &zj[li * ZJ_STRIDE + kt * 32 + q * 8];
            bf16x8 b0 = *reinterpret_cast<const bf16x8*>(bp);
            bf16x8 b1 = *reinterpret_cast<const bf16x8*>(bp + 16 * ZJ_STRIDE);
            bf16x8 b2 = *reinterpret_cast<const bf16x8*>(bp + 32 * ZJ_STRIDE);
            bf16x8 b3 = *reinterpret_cast<const bf16x8*>(bp + 48 * ZJ_STRIDE);
            acc0 = __builtin_amdgcn_mfma_f32_16x16x32_bf16(afrag[kt], b0, acc0, 0, 0, 0);
            acc1 = __builtin_amdgcn_mfma_f32_16x16x32_bf16(afrag[kt], b1, acc1, 0, 0, 0);
            acc2 = __builtin_amdgcn_mfma_f32_16x16x32_bf16(afrag[kt], b2, acc2, 0, 0, 0);
            acc3 = __builtin_amdgcn_mfma_f32_16x16x32_bf16(afrag[kt], b3, acc3, 0, 0, 0);
        }
        // C/D layout (m89-verified): col = lane&15, row = quad*4 + reg
#pragma unroll
        for (int r = 0; r < 4; ++r) {
            part[r] += __expf(acc0[r] * 2.0f - 2.0f);
            part[r] += __expf(acc1[r] * 2.0f - 2.0f);
            part[r] += __expf(acc2[r] * 2.0f - 2.0f);
            part[r] += __expf(acc3[r] * 2.0f - 2.0f);
        }
    }

    // Reduce across the 16 lanes holding different cols of the same rows.
#pragma unroll
    for (int r = 0; r < 4; ++r) {
        float v = part[r];
        v += __shfl_xor(v, 1);
        v += __shfl_xor(v, 2);
        v += __shfl_xor(v, 4);
        v += __shfl_xor(v, 8);
        if (li == 0) atomicAdd(&rowsum[i0 + wave * 16 + q * 4 + r], v);
    }
}

// lse_i = 2 + log(rowsum_i - 1)  (subtract diag's exp(0)=1); loss = mean(lse - pos)
__global__ void k_final(const float* __restrict__ rowsum, const float* __restrict__ pos_sum,
                        float* __restrict__ out) {
    int t = threadIdx.x;
    float acc = 0.0f;
    for (int i = t; i < M_TOT; i += 256)
        acc += 2.0f + __logf(rowsum[i] - 1.0f);
    acc = wave_reduce_sum(acc);
    __shared__ float wsum[4];
    if ((t & 63) == 0) wsum[t >> 6] = acc;
    __syncthreads();
    if (t == 0) {
        float tot = wsum[0] + wsum[1] + wsum[2] + wsum[3];
        out[0] = (tot - pos_sum[0]) / (float)M_TOT;
    }
}

extern "C" void kernel_launch(void* const* d_in, const int* in_sizes, int n_in,
                              void* d_out, int out_size, void* d_ws, size_t ws_size,
                              hipStream_t stream) {
    const float* zis = (const float*)d_in[0];
    const float* zjs = (const float*)d_in[1];
    char* ws = (char*)d_ws;
    __hip_bfloat16* zn = (__hip_bfloat16*)ws;                       // 4 MB
    float* rowsum  = (float*)(ws + (size_t)M_TOT * D * 2);          // 32 KB
    float* pos_sum = rowsum + M_TOT;                                // 4 B
    float* out = (float*)d_out;

    k_init<<<(M_TOT + 1 + 255) / 256, 256, 0, stream>>>(rowsum, M_TOT + 1);
    k_norm<<<M_TOT, 256, 0, stream>>>(zis, zjs, zn);
    k_pos<<<N_HALF / 4, 256, 0, stream>>>(zn, pos_sum);
    dim3 grid(M_TOT / TI, M_TOT / JCHUNK);
    k_main<<<grid, 256, 0, stream>>>(zn, rowsum);
    k_final<<<1, 256, 0, stream>>>(rowsum, pos_sum, out);
}

// Round 2
// 126.926 us; speedup vs baseline: 1.4130x; 1.4130x over previous
//
#include <hip/hip_runtime.h>
#include <hip/hip_bf16.h>

#define N_HALF 4096
#define M_TOT  8192
#define D      256
#define TJ     64          // j-rows staged in LDS per jt
#define JCHUNK 512         // j-cols per block
#define ZJ_STRIDE 264      // 256 + 8 bf16 pad (row = 528 B, 16B-aligned)

typedef __attribute__((ext_vector_type(8))) short bf16x8;
typedef __attribute__((ext_vector_type(4))) float f32x4;

__device__ __forceinline__ float wave_reduce_sum(float v) {
    v += __shfl_xor(v, 1);
    v += __shfl_xor(v, 2);
    v += __shfl_xor(v, 4);
    v += __shfl_xor(v, 8);
    v += __shfl_xor(v, 16);
    v += __shfl_xor(v, 32);
    return v;
}

// Fused: normalize both rows of pair r (reps row r = zjs[r], row r+N = zis[r]),
// compute the positive-pair dot in fp32, zero rowsum entries (safe: stream order
// guarantees k_prep completes before k_main's atomics).
__global__ void k_prep(const float* __restrict__ zis, const float* __restrict__ zjs,
                       __hip_bfloat16* __restrict__ zn, float* __restrict__ rowsum,
                       float* __restrict__ pos_part) {
    int r = blockIdx.x;        // 0..4095
    int t = threadIdx.x;       // 0..255
    float zi = zis[(size_t)r * D + t];
    float zj = zjs[(size_t)r * D + t];
    float ssi = wave_reduce_sum(zi * zi);
    float ssj = wave_reduce_sum(zj * zj);
    float dd  = wave_reduce_sum(zi * zj);
    __shared__ float red[3][4];
    int w = t >> 6;
    if ((t & 63) == 0) { red[0][w] = ssi; red[1][w] = ssj; red[2][w] = dd; }
    __syncthreads();
    float ni = fmaxf(sqrtf(red[0][0] + red[0][1] + red[0][2] + red[0][3]), 1e-8f);
    float nj = fmaxf(sqrtf(red[1][0] + red[1][1] + red[1][2] + red[1][3]), 1e-8f);
    zn[(size_t)r * D + t]            = __float2bfloat16(zj / nj);
    zn[(size_t)(r + N_HALF) * D + t] = __float2bfloat16(zi / ni);
    if (t == 0) {
        float dot = red[2][0] + red[2][1] + red[2][2] + red[2][3];
        // sum over all 2N rows of pos_i = sim/T ; each unordered pair twice -> *4
        pos_part[r] = dot / (ni * nj) * 4.0f;
        rowsum[r] = 0.0f;
        rowsum[r + N_HALF] = 0.0f;
    }
}

// Fused sim + exp + row-sum, register-blocked A.
// Block: 256 thr = 4 waves; block tile = 256 i-rows x 512 j-cols.
// Wave w owns i-rows [blk*256 + w*64, +64) as 4 MFMA i-tiles whose A fragments
// (full K=256) live in 128 VGPRs -> each LDS B-frag read feeds 4 MFMAs.
// rowsum[i] += sum_j exp(sim_ij*2 - 2)   (diag included; subtract 1 in k_final)
__global__ __launch_bounds__(256, 2)
void k_main(const __hip_bfloat16* __restrict__ znh, float* __restrict__ rowsum) {
    __shared__ __align__(16) ushort zj[TJ * ZJ_STRIDE];   // 33792 B
    const ushort* zn = reinterpret_cast<const ushort*>(znh);
    int tid  = threadIdx.x;
    int wave = tid >> 6;
    int lane = tid & 63;
    int q    = lane >> 4;   // quad
    int li   = lane & 15;
    int i_base = blockIdx.x * 256 + wave * 64;
    int j0     = blockIdx.y * JCHUNK;

    // A fragment (16x16x32 bf16): A[m][k], m = lane&15, k = quad*8 + j
    bf16x8 afrag[4][8];
#pragma unroll
    for (int it = 0; it < 4; ++it) {
        const ushort* ap = zn + (((size_t)(i_base + it * 16 + li)) << 8) + q * 8;
#pragma unroll
        for (int kt = 0; kt < 8; ++kt)
            afrag[it][kt] = *reinterpret_cast<const bf16x8*>(ap + kt * 32);
    }

    float part[4][4];   // [i_tile][reg-row]
#pragma unroll
    for (int it = 0; it < 4; ++it)
#pragma unroll
        for (int r = 0; r < 4; ++r) part[it][r] = 0.0f;

    for (int jt = 0; jt < JCHUNK / TJ; ++jt) {
        __syncthreads();   // previous iteration's reads done before overwrite
        {
            int base = j0 + jt * TJ;
#pragma unroll
            for (int s = 0; s < 8; ++s) {
                int e  = (s * 256 + tid) * 8;
                int rr = e >> 8;
                int cc = e & 255;
                *reinterpret_cast<uint4*>(&zj[rr * ZJ_STRIDE + cc]) =
                    *reinterpret_cast<const uint4*>(zn + (((size_t)(base + rr)) << 8) + cc);
            }
        }
        __syncthreads();

#pragma unroll
        for (int jtile = 0; jtile < 4; ++jtile) {
            f32x4 acc[4] = {{0,0,0,0},{0,0,0,0},{0,0,0,0},{0,0,0,0}};
#pragma unroll
            for (int kt = 0; kt < 8; ++kt) {
                // B frag: B[k][n], n = li -> zj row (jtile*16 + li), k = kt*32 + q*8
                bf16x8 b = *reinterpret_cast<const bf16x8*>(
                    &zj[(jtile * 16 + li) * ZJ_STRIDE + kt * 32 + q * 8]);
#pragma unroll
                for (int it = 0; it < 4; ++it)
                    acc[it] = __builtin_amdgcn_mfma_f32_16x16x32_bf16(
                        afrag[it][kt], b, acc[it], 0, 0, 0);
            }
            // C/D layout (m89-verified): col = lane&15, row = quad*4 + reg
#pragma unroll
            for (int it = 0; it < 4; ++it)
#pragma unroll
                for (int r = 0; r < 4; ++r)
                    part[it][r] += __expf(acc[it][r] * 2.0f - 2.0f);
        }
    }

    // Reduce across the 16 lanes holding different j-cols of the same rows.
#pragma unroll
    for (int it = 0; it < 4; ++it)
#pragma unroll
        for (int r = 0; r < 4; ++r) {
            float v = part[it][r];
            v += __shfl_xor(v, 1);
            v += __shfl_xor(v, 2);
            v += __shfl_xor(v, 4);
            v += __shfl_xor(v, 8);
            if (li == 0) atomicAdd(&rowsum[i_base + it * 16 + q * 4 + r], v);
        }
}

// lse_i = 2 + log(rowsum_i - 1); loss = (sum lse - sum pos)/M
__global__ void k_final(const float* __restrict__ rowsum, const float* __restrict__ pos_part,
                        float* __restrict__ out) {
    int t = threadIdx.x;
    float acc = 0.0f;
    for (int i = t; i < M_TOT; i += 256)
        acc += 2.0f + __logf(rowsum[i] - 1.0f);
    float pacc = 0.0f;
    for (int i = t; i < N_HALF; i += 256)
        pacc += pos_part[i];
    acc  = wave_reduce_sum(acc);
    pacc = wave_reduce_sum(pacc);
    __shared__ float wsum[4], psum[4];
    if ((t & 63) == 0) { wsum[t >> 6] = acc; psum[t >> 6] = pacc; }
    __syncthreads();
    if (t == 0) {
        float tot = wsum[0] + wsum[1] + wsum[2] + wsum[3];
        float pt  = psum[0] + psum[1] + psum[2] + psum[3];
        out[0] = (tot - pt) / (float)M_TOT;
    }
}

extern "C" void kernel_launch(void* const* d_in, const int* in_sizes, int n_in,
                              void* d_out, int out_size, void* d_ws, size_t ws_size,
                              hipStream_t stream) {
    const float* zis = (const float*)d_in[0];
    const float* zjs = (const float*)d_in[1];
    char* ws = (char*)d_ws;
    __hip_bfloat16* zn = (__hip_bfloat16*)ws;                         // 4 MB
    float* rowsum   = (float*)(ws + (size_t)M_TOT * D * 2);           // 32 KB
    float* pos_part = rowsum + M_TOT;                                 // 16 KB
    float* out = (float*)d_out;

    k_prep<<<N_HALF, 256, 0, stream>>>(zis, zjs, zn, rowsum, pos_part);
    dim3 grid(M_TOT / 256, M_TOT / JCHUNK);
    k_main<<<grid, 256, 0, stream>>>(zn, rowsum);
    k_final<<<1, 256, 0, stream>>>(rowsum, pos_part, out);
}